// Round 6
// baseline (927.509 us; speedup 1.0000x reference)
//
#include <hip/hip_runtime.h>

// Problem constants
#define BATCH 32
#define INCH 12
#define OUTCH 16
#define H 384
#define W 384
#define OH 192
#define OW 192

// Workspace float offsets
#define WS_ACTSUM 0        // 512 floats  (b,oc) sums of activated
#define WS_POOLED 512      // 384 floats  (b,c) sums of x
#define WS_SCALE  896      // 512 floats  1 + gating
#define WS_RPROJ  1408     // 512 floats  res projection
#define WS_WT     1920     // 4800 floats transposed weight [300][16]

__global__ __launch_bounds__(256)
void init_ws(const float* __restrict__ weight, float* __restrict__ ws) {
    int idx = blockIdx.x * 256 + threadIdx.x;
    if (idx < 896) ws[idx] = 0.f;
    if (idx < 4800) {
        int oc = idx / 300, k = idx - oc * 300;
        ws[WS_WT + k * 16 + oc] = weight[idx];
    }
}

// One block: 32-wide x 16-tall output tile, all 16 output channels.
// Thread = 1 output row x 2 adjacent output cols x 16 oc (acc[2][16]).
// LDS: input tile 35x67, de-interleaved by column parity so (a) stride-2
// tap reads are conflict-free and (b) the 2 cols of a thread's pair are
// ADJACENT in LDS -> one fused 8B read feeds 32 FMAs.
__global__ __launch_bounds__(256, 6)
void conv_act(const float* __restrict__ x,
              const float* __restrict__ wT,
              const float* __restrict__ bias,
              float* __restrict__ actsum,
              float* __restrict__ pooled,
              float* __restrict__ out) {
    __shared__ float lds[2][35][34];
    __shared__ float ps[INCH][4];    // per-wave pooled partials
    __shared__ float as_[OUTCH][4];  // per-wave actsum partials

    const int tile = blockIdx.x;           // 0..71
    const int b    = blockIdx.y;           // 0..31
    const int ty = tile / 6, tx = tile - ty * 6;
    const int oh0 = ty * 16, ow0 = tx * 32;
    const int ib_r = oh0 * 2 - 2;          // input tile base row (may be -2)
    const int ib_c = ow0 * 2 - 2;

    const int t    = threadIdx.x;
    const int cp   = t & 15;               // col pair: out cols 2cp, 2cp+1
    const int rr   = t >> 4;               // out row 0..15
    const int wave = t >> 6;
    const int lane = t & 63;

    float acc[2][16];
#pragma unroll
    for (int m = 0; m < 2; ++m)
#pragma unroll
        for (int o = 0; o < 16; ++o) acc[m][o] = 0.f;

    for (int c = 0; c < INCH; ++c) {
        const float* xc = x + ((size_t)(b * INCH + c)) * (H * W);
        float psum = 0.f;
        for (int i = t; i < 35 * 67; i += 256) {
            int row = i / 67;
            int col = i - row * 67;
            int ih = ib_r + row, iw = ib_c + col;
            float v = 0.f;
            if ((unsigned)ih < (unsigned)H && (unsigned)iw < (unsigned)W)
                v = xc[ih * W + iw];
            lds[col & 1][row][col >> 1] = v;
            // exclusive 32x64 input region (rel rows 2..33, cols 2..65)
            if (row >= 2 && row <= 33 && col >= 2 && col <= 65) psum += v;
        }
#pragma unroll
        for (int off = 32; off; off >>= 1) psum += __shfl_down(psum, off);
        if (lane == 0) ps[c][wave] = psum;
        __syncthreads();

#pragma unroll
        for (int ky = 0; ky < 5; ++ky) {
            const float* Lr0 = &lds[0][2 * rr + ky][0];
            const float* Lr1 = &lds[1][2 * rr + ky][0];
#pragma unroll
            for (int kx = 0; kx < 5; ++kx) {
                const float* wp = wT + (c * 25 + ky * 5 + kx) * 16;
                const float* Lr = (kx & 1) ? Lr1 : Lr0;
                const int a0 = (kx >> 1) + 2 * cp;
                float va = Lr[a0];
                float vb = Lr[a0 + 1];
#pragma unroll
                for (int o = 0; o < 16; ++o) {
                    float wv = wp[o];
                    acc[0][o] = fmaf(va, wv, acc[0][o]);
                    acc[1][o] = fmaf(vb, wv, acc[1][o]);
                }
            }
        }
        __syncthreads();
    }

    // bias + hardswish, store activated (fp32), per-wave actsum partials
    const size_t base = ((size_t)b * OUTCH) * (OH * OW)
                      + (size_t)(oh0 + rr) * OW + ow0 + 2 * cp;
#pragma unroll
    for (int o = 0; o < 16; ++o) {
        float a0v = acc[0][o] + bias[o];
        float a1v = acc[1][o] + bias[o];
        float h0 = a0v * fminf(fmaxf(a0v + 3.f, 0.f), 6.f) * (1.f / 6.f);
        float h1 = a1v * fminf(fmaxf(a1v + 3.f, 0.f), 6.f) * (1.f / 6.f);
        float2 st; st.x = h0; st.y = h1;
        *reinterpret_cast<float2*>(&out[base + (size_t)o * (OH * OW)]) = st;
        float s = h0 + h1;
#pragma unroll
        for (int off = 32; off; off >>= 1) s += __shfl_down(s, off);
        if (lane == 0) as_[o][wave] = s;
    }
    __syncthreads();
    if (t < INCH)
        atomicAdd(&pooled[b * INCH + t], ps[t][0] + ps[t][1] + ps[t][2] + ps[t][3]);
    if (t >= 32 && t < 32 + OUTCH) {
        int o = t - 32;
        atomicAdd(&actsum[b * OUTCH + o], as_[o][0] + as_[o][1] + as_[o][2] + as_[o][3]);
    }
}

__global__ __launch_bounds__(512)
void finalize(const float* __restrict__ actsum,
              const float* __restrict__ pooled,
              const float* __restrict__ res_w,
              float* __restrict__ scale,
              float* __restrict__ rproj) {
    int t = threadIdx.x;          // 512 = 32 b * 16 oc
    int b = t >> 4, oc = t & 15;
    float mean = actsum[t] * (1.f / (OH * OW));
    float g = fminf(fmaxf(mean, -0.5f), 0.5f);
    scale[t] = 1.f + g;
    float rp = 0.f;
#pragma unroll
    for (int c = 0; c < INCH; ++c)
        rp += pooled[b * INCH + c] * res_w[oc * INCH + c];
    rproj[t] = rp * (1.f / (H * W));
}

// grid (512, 4): quarter of a (b,oc) plane per block.
__global__ __launch_bounds__(256)
void epilogue(float* __restrict__ out,
              const float* __restrict__ scale,
              const float* __restrict__ rproj) {
    const int bo = blockIdx.x;            // 0..511
    const float s  = scale[bo];
    const float rp = rproj[bo];
    float4* p = reinterpret_cast<float4*>(out)
              + (size_t)bo * (OH * OW / 4) + (size_t)blockIdx.y * (OH * OW / 16);
    for (int i = threadIdx.x; i < OH * OW / 16; i += 256) {
        float4 v = p[i];
        v.x = fminf(fmaxf(fmaf(v.x, s, rp), -0.5f), 0.5f);
        v.y = fminf(fmaxf(fmaf(v.y, s, rp), -0.5f), 0.5f);
        v.z = fminf(fmaxf(fmaf(v.z, s, rp), -0.5f), 0.5f);
        v.w = fminf(fmaxf(fmaf(v.w, s, rp), -0.5f), 0.5f);
        p[i] = v;
    }
}

extern "C" void kernel_launch(void* const* d_in, const int* in_sizes, int n_in,
                              void* d_out, int out_size, void* d_ws, size_t ws_size,
                              hipStream_t stream) {
    const float* x      = (const float*)d_in[0];
    const float* weight = (const float*)d_in[1];
    const float* bias   = (const float*)d_in[2];
    const float* res_w  = (const float*)d_in[3];
    float* out = (float*)d_out;
    float* ws  = (float*)d_ws;

    init_ws<<<19, 256, 0, stream>>>(weight, ws);

    dim3 grid(72, 32);
    conv_act<<<grid, 256, 0, stream>>>(x, ws + WS_WT, bias,
                                       ws + WS_ACTSUM, ws + WS_POOLED, out);

    finalize<<<1, 512, 0, stream>>>(ws + WS_ACTSUM, ws + WS_POOLED, res_w,
                                    ws + WS_SCALE, ws + WS_RPROJ);

    epilogue<<<dim3(512, 4), 256, 0, stream>>>(out, ws + WS_SCALE, ws + WS_RPROJ);
}

// Round 7
// 852.548 us; speedup vs baseline: 1.0879x; 1.0879x over previous
//
#include <hip/hip_runtime.h>

// Problem constants
#define BATCH 32
#define INCH 12
#define OUTCH 16
#define H 384
#define W 384
#define OH 192
#define OW 192

// Workspace float offsets
#define WS_ACTSUM 0      // 512 floats  (b,oc) sums of activated
#define WS_POOLED 512    // 384 floats  (b,c) sums of x
#define WS_WT 1024       // 4800 floats transposed weight [300 taps][16 oc]

__global__ __launch_bounds__(256)
void init_ws(const float* __restrict__ weight, float* __restrict__ ws) {
    int idx = blockIdx.x * 256 + threadIdx.x;
    if (idx < 1024) ws[idx] = 0.f;
    if (idx < 4800) {
        int oc = idx / 300, k = idx - oc * 300;
        ws[WS_WT + k * 16 + oc] = weight[idx];
    }
}

// Thread = 2 rows x 2 cols x 16 oc. No LDS input staging: direct global
// reads (L1-resident, immediate offsets). Per tap: 4 input loads + 4
// uniform float4 weight loads feed 64 FMAs.
template<bool EDGE>
__device__ __forceinline__ void conv_core(
    const float* __restrict__ x, const float* __restrict__ wT,
    const float* __restrict__ bias, float* __restrict__ actsum,
    float* __restrict__ pooled, float* __restrict__ out,
    int b, int oh0, int ow0)
{
    __shared__ float ps[INCH][4];
    __shared__ float as_[OUTCH][4];

    const int t = threadIdx.x;
    const int cp = t & 15;           // col group: out cols 2cp, 2cp+1
    const int rw = t >> 4;           // row group: out rows 2rw, 2rw+1
    const int wave = t >> 6;
    const int lane = t & 63;

    const int ihb = oh0 * 2 + rw * 4 - 2;   // input row for j=0
    const int iwb = ow0 * 2 + cp * 4 - 2;   // input col for k=0

    float acc[2][2][16];
#pragma unroll
    for (int dr = 0; dr < 2; ++dr)
#pragma unroll
        for (int dc = 0; dc < 2; ++dc)
#pragma unroll
            for (int o = 0; o < 16; ++o) acc[dr][dc][o] = 0.f;

    int rofs[7];
    int cix[7];
    float rvf[7], cvf[7];
#pragma unroll
    for (int j = 0; j < 7; ++j) {
        int ih = ihb + j;
        if (EDGE) {
            rvf[j] = ((unsigned)ih < (unsigned)H) ? 1.f : 0.f;
            int ihc = ih < 0 ? 0 : (ih > H - 1 ? H - 1 : ih);
            rofs[j] = ihc * W;
            int iw = iwb + j;
            cvf[j] = ((unsigned)iw < (unsigned)W) ? 1.f : 0.f;
            cix[j] = iw < 0 ? 0 : (iw > W - 1 ? W - 1 : iw);
        } else {
            rofs[j] = ih * W;
        }
    }

#pragma unroll 1
    for (int c = 0; c < INCH; ++c) {
        const float* xc = x + (size_t)(b * INCH + c) * (H * W);

#pragma unroll
        for (int ky = 0; ky < 5; ++ky) {
#pragma unroll
            for (int kx = 0; kx < 5; ++kx) {
                const float4* w4p = reinterpret_cast<const float4*>(
                    wT + (c * 25 + ky * 5 + kx) * 16);
                float warr[16];
#pragma unroll
                for (int q = 0; q < 4; ++q)
                    *reinterpret_cast<float4*>(&warr[4 * q]) = w4p[q];

                float in00, in01, in10, in11;
                if (EDGE) {
                    in00 = xc[rofs[ky]     + cix[kx]]     * (rvf[ky]     * cvf[kx]);
                    in01 = xc[rofs[ky]     + cix[kx + 2]] * (rvf[ky]     * cvf[kx + 2]);
                    in10 = xc[rofs[ky + 2] + cix[kx]]     * (rvf[ky + 2] * cvf[kx]);
                    in11 = xc[rofs[ky + 2] + cix[kx + 2]] * (rvf[ky + 2] * cvf[kx + 2]);
                } else {
                    in00 = xc[rofs[ky]     + iwb + kx];
                    in01 = xc[rofs[ky]     + iwb + kx + 2];
                    in10 = xc[rofs[ky + 2] + iwb + kx];
                    in11 = xc[rofs[ky + 2] + iwb + kx + 2];
                }
#pragma unroll
                for (int o = 0; o < 16; ++o) {
                    float wo = warr[o];
                    acc[0][0][o] = fmaf(in00, wo, acc[0][0][o]);
                    acc[0][1][o] = fmaf(in01, wo, acc[0][1][o]);
                    acc[1][0][o] = fmaf(in10, wo, acc[1][0][o]);
                    acc[1][1][o] = fmaf(in11, wo, acc[1][1][o]);
                }
            }
        }

        // pooled-x partial: exclusive 4x4 patch (always interior), L1-hot
        const float* pp = xc + (size_t)(oh0 * 2 + rw * 4) * W + (ow0 * 2 + cp * 4);
        float psum = 0.f;
#pragma unroll
        for (int i = 0; i < 4; ++i) {
            float4 v = *reinterpret_cast<const float4*>(pp + i * W);
            psum += (v.x + v.y) + (v.z + v.w);
        }
#pragma unroll
        for (int off = 32; off; off >>= 1) psum += __shfl_down(psum, off);
        if (lane == 0) ps[c][wave] = psum;
    }

    // bias + hardswish + store + per-oc sums
#pragma unroll
    for (int o = 0; o < 16; ++o) {
        float bo = bias[o];
        float osum = 0.f;
#pragma unroll
        for (int dr = 0; dr < 2; ++dr) {
            float a0 = acc[dr][0][o] + bo;
            float a1 = acc[dr][1][o] + bo;
            float h0 = a0 * fminf(fmaxf(a0 + 3.f, 0.f), 6.f) * (1.f / 6.f);
            float h1 = a1 * fminf(fmaxf(a1 + 3.f, 0.f), 6.f) * (1.f / 6.f);
            float2 st; st.x = h0; st.y = h1;
            *reinterpret_cast<float2*>(
                &out[(((size_t)b * OUTCH + o) * OH + (oh0 + 2 * rw + dr)) * OW
                     + ow0 + 2 * cp]) = st;
            osum += h0 + h1;
        }
#pragma unroll
        for (int off = 32; off; off >>= 1) osum += __shfl_down(osum, off);
        if (lane == 0) as_[o][wave] = osum;
    }
    __syncthreads();
    if (t < INCH)
        atomicAdd(&pooled[b * INCH + t], ps[t][0] + ps[t][1] + ps[t][2] + ps[t][3]);
    if (t >= 32 && t < 32 + OUTCH) {
        int o = t - 32;
        atomicAdd(&actsum[b * OUTCH + o], as_[o][0] + as_[o][1] + as_[o][2] + as_[o][3]);
    }
}

__global__ __launch_bounds__(256, 3)
void conv_act(const float* __restrict__ x,
              const float* __restrict__ wT,
              const float* __restrict__ bias,
              float* __restrict__ actsum,
              float* __restrict__ pooled,
              float* __restrict__ out) {
    const int ty = blockIdx.x / 6, tx = blockIdx.x % 6;
    const int b = blockIdx.y;
    const int oh0 = ty * 32, ow0 = tx * 32;
    if (ty == 0 || ty == 5 || tx == 0 || tx == 5)
        conv_core<true>(x, wT, bias, actsum, pooled, out, b, oh0, ow0);
    else
        conv_core<false>(x, wT, bias, actsum, pooled, out, b, oh0, ow0);
}

// Fused finalize+epilogue: each block derives scale/rproj (28 tiny reads),
// then rescales+clips its slice of the plane.
__global__ __launch_bounds__(256)
void epilogue(float* __restrict__ out,
              const float* __restrict__ actsum,
              const float* __restrict__ pooled,
              const float* __restrict__ res_w) {
    const int bo = blockIdx.x;            // b*16+oc, 0..511
    const int b = bo >> 4, oc = bo & 15;
    float mean = actsum[bo] * (1.f / (OH * OW));
    float s = 1.f + fminf(fmaxf(mean, -0.5f), 0.5f);
    float rp = 0.f;
#pragma unroll
    for (int c = 0; c < INCH; ++c)
        rp += pooled[b * INCH + c] * res_w[oc * INCH + c];
    rp *= (1.f / (H * W));

    float4* p = reinterpret_cast<float4*>(out)
              + (size_t)bo * (OH * OW / 4) + (size_t)blockIdx.y * (OH * OW / 16);
    for (int i = threadIdx.x; i < OH * OW / 16; i += 256) {
        float4 v = p[i];
        v.x = fminf(fmaxf(fmaf(v.x, s, rp), -0.5f), 0.5f);
        v.y = fminf(fmaxf(fmaf(v.y, s, rp), -0.5f), 0.5f);
        v.z = fminf(fmaxf(fmaf(v.z, s, rp), -0.5f), 0.5f);
        v.w = fminf(fmaxf(fmaf(v.w, s, rp), -0.5f), 0.5f);
        p[i] = v;
    }
}

extern "C" void kernel_launch(void* const* d_in, const int* in_sizes, int n_in,
                              void* d_out, int out_size, void* d_ws, size_t ws_size,
                              hipStream_t stream) {
    const float* x      = (const float*)d_in[0];
    const float* weight = (const float*)d_in[1];
    const float* bias   = (const float*)d_in[2];
    const float* res_w  = (const float*)d_in[3];
    float* out = (float*)d_out;
    float* ws  = (float*)d_ws;

    init_ws<<<19, 256, 0, stream>>>(weight, ws);

    conv_act<<<dim3(36, 32), 256, 0, stream>>>(x, ws + WS_WT, bias,
                                               ws + WS_ACTSUM, ws + WS_POOLED, out);

    epilogue<<<dim3(512, 4), 256, 0, stream>>>(out, ws + WS_ACTSUM,
                                               ws + WS_POOLED, res_w);
}

// Round 8
// 570.453 us; speedup vs baseline: 1.6259x; 1.4945x over previous
//
#include <hip/hip_runtime.h>

// Problem constants
#define BATCH 32
#define INCH 12
#define OUTCH 16
#define H 384
#define W 384
#define OH 192
#define OW 192

#define IN_T 67          // input tile dim (32x32 out tile, stride 2, 5x5)
#define LDS_S 69         // LDS row stride (odd-ish => conflict-free tap reads)
#define NSTG 18          // ceil(67*67/256) staging loads per thread

// Workspace float offsets
#define WS_ACTSUM 0      // 512 floats  (b,oc) sums of activated
#define WS_POOLED 512    // 384 floats  (b,c) sums of x
#define WS_WT 1024       // 4800 floats transposed weight [300 taps][16 oc]

__global__ __launch_bounds__(256)
void init_ws(const float* __restrict__ weight, float* __restrict__ ws) {
    int idx = blockIdx.x * 256 + threadIdx.x;
    if (idx < 1024) ws[idx] = 0.f;
    if (idx < 4800) {
        int oc = idx / 300, k = idx - oc * 300;
        ws[WS_WT + k * 16 + oc] = weight[idx];
    }
}

// 32x32 output tile, all 16 oc per block. Thread = 4 rows x 1 col x 16 oc
// (acc[4][16], 64 FMA per tap from 4 ds_read_b32 w/ immediate offsets).
// Double-buffered LDS + async reg-staging: per channel, global loads are
// issued BEFORE the tap compute (latency hides under 3200 VALU-cycles),
// ds_write + ONE barrier after.
template<bool EDGE>
__device__ __forceinline__ void conv_core(
    const float* __restrict__ x, const float* __restrict__ wT,
    const float* __restrict__ bias, float* __restrict__ actsum,
    float* __restrict__ pooled, float* __restrict__ out,
    int b, int oh0, int ow0)
{
    __shared__ float lds[2][IN_T][LDS_S];
    __shared__ float ps[INCH][4];
    __shared__ float as_[OUTCH][4];

    const int t = threadIdx.x;
    const int cc = t & 31;           // out col within tile
    const int r4 = t >> 5;           // row group: rows 4*r4 .. 4*r4+3
    const int wave = t >> 6;
    const int lane = t & 63;

    const int ib_r = oh0 * 2 - 2;
    const int ib_c = ow0 * 2 - 2;

    const float* xb = x + (size_t)(b * INCH) * (H * W);

    float acc[4][16];
#pragma unroll
    for (int m = 0; m < 4; ++m)
#pragma unroll
        for (int o = 0; o < 16; ++o) acc[m][o] = 0.f;

    float sv[NSTG];

    // --- staging helpers ---
    auto stage_load = [&](int c) {
        const float* xc = xb + (size_t)c * (H * W);
#pragma unroll
        for (int i = 0; i < NSTG; ++i) {
            int idx = t + i * 256;
            int row = (int)((unsigned)idx / 67u);
            int col = idx - row * 67;
            int ih = ib_r + row, iw = ib_c + col;
            float v = 0.f;
            if (EDGE) {
                if ((i < NSTG - 1 || idx < IN_T * IN_T) &&
                    (unsigned)ih < (unsigned)H && (unsigned)iw < (unsigned)W)
                    v = xc[ih * W + iw];
            } else {
                if (i < NSTG - 1 || idx < IN_T * IN_T)
                    v = xc[ih * W + iw];
            }
            sv[i] = v;
        }
    };
    auto stage_write = [&](int buf, int c) {
        float psum = 0.f;
#pragma unroll
        for (int i = 0; i < NSTG; ++i) {
            int idx = t + i * 256;
            int row = (int)((unsigned)idx / 67u);
            int col = idx - row * 67;
            if (i < NSTG - 1 || idx < IN_T * IN_T) {
                lds[buf][row][col] = sv[i];
                // exclusive 64x64 interior region partitions the image
                if ((unsigned)(row - 2) < 64u && (unsigned)(col - 2) < 64u)
                    psum += sv[i];
            }
        }
#pragma unroll
        for (int off = 32; off; off >>= 1) psum += __shfl_down(psum, off);
        if (lane == 0) ps[c][wave] = psum;
    };

    // prologue: channel 0
    stage_load(0);
    stage_write(0, 0);
    __syncthreads();

    const float* lbase0 = &lds[0][0][0] + (8 * r4) * LDS_S + 2 * cc;
    const float* lbase1 = &lds[1][0][0] + (8 * r4) * LDS_S + 2 * cc;

#pragma unroll 1
    for (int c = 0; c < INCH; ++c) {
        const int cur = c & 1;
        if (c + 1 < INCH) stage_load(c + 1);   // issue early: hide under FMAs

        const float* lb = cur ? lbase1 : lbase0;
        const float* wc = wT + c * 25 * 16;
#pragma unroll
        for (int ky = 0; ky < 5; ++ky) {
#pragma unroll
            for (int kx = 0; kx < 5; ++kx) {
                const float4* wq =
                    reinterpret_cast<const float4*>(wc + (ky * 5 + kx) * 16);
                float4 w0 = wq[0], w1 = wq[1], w2 = wq[2], w3 = wq[3];
                float in0 = lb[(0 + ky) * LDS_S + kx];
                float in1 = lb[(2 + ky) * LDS_S + kx];
                float in2 = lb[(4 + ky) * LDS_S + kx];
                float in3 = lb[(6 + ky) * LDS_S + kx];
                const float wv[16] = {w0.x, w0.y, w0.z, w0.w,
                                      w1.x, w1.y, w1.z, w1.w,
                                      w2.x, w2.y, w2.z, w2.w,
                                      w3.x, w3.y, w3.z, w3.w};
#pragma unroll
                for (int o = 0; o < 16; ++o) {
                    acc[0][o] = fmaf(in0, wv[o], acc[0][o]);
                    acc[1][o] = fmaf(in1, wv[o], acc[1][o]);
                    acc[2][o] = fmaf(in2, wv[o], acc[2][o]);
                    acc[3][o] = fmaf(in3, wv[o], acc[3][o]);
                }
            }
        }

        if (c + 1 < INCH) stage_write(cur ^ 1, c + 1);
        __syncthreads();
    }

    // bias + hardswish + store + per-oc sums
#pragma unroll
    for (int o = 0; o < 16; ++o) {
        float bo = bias[o];
        float osum = 0.f;
#pragma unroll
        for (int m = 0; m < 4; ++m) {
            float a = acc[m][o] + bo;
            float h = a * fminf(fmaxf(a + 3.f, 0.f), 6.f) * (1.f / 6.f);
            out[(((size_t)b * OUTCH + o) * OH + (oh0 + 4 * r4 + m)) * OW
                + ow0 + cc] = h;
            osum += h;
        }
#pragma unroll
        for (int off = 32; off; off >>= 1) osum += __shfl_down(osum, off);
        if (lane == 0) as_[o][wave] = osum;
    }
    __syncthreads();
    if (t < INCH)
        atomicAdd(&pooled[b * INCH + t], ps[t][0] + ps[t][1] + ps[t][2] + ps[t][3]);
    if (t >= 32 && t < 32 + OUTCH) {
        int o = t - 32;
        atomicAdd(&actsum[b * OUTCH + o], as_[o][0] + as_[o][1] + as_[o][2] + as_[o][3]);
    }
}

__global__ __launch_bounds__(256, 4)
void conv_act(const float* __restrict__ x,
              const float* __restrict__ wT,
              const float* __restrict__ bias,
              float* __restrict__ actsum,
              float* __restrict__ pooled,
              float* __restrict__ out) {
    const int ty = blockIdx.x / 6, tx = blockIdx.x % 6;
    const int b = blockIdx.y;
    const int oh0 = ty * 32, ow0 = tx * 32;
    if (ty == 0 || ty == 5 || tx == 0 || tx == 5)
        conv_core<true>(x, wT, bias, actsum, pooled, out, b, oh0, ow0);
    else
        conv_core<false>(x, wT, bias, actsum, pooled, out, b, oh0, ow0);
}

// Fused finalize+epilogue: each block derives scale/rproj (28 tiny reads),
// then rescales+clips its slice of the plane.
__global__ __launch_bounds__(256)
void epilogue(float* __restrict__ out,
              const float* __restrict__ actsum,
              const float* __restrict__ pooled,
              const float* __restrict__ res_w) {
    const int bo = blockIdx.x;            // b*16+oc, 0..511
    const int b = bo >> 4, oc = bo & 15;
    float mean = actsum[bo] * (1.f / (OH * OW));
    float s = 1.f + fminf(fmaxf(mean, -0.5f), 0.5f);
    float rp = 0.f;
#pragma unroll
    for (int c = 0; c < INCH; ++c)
        rp += pooled[b * INCH + c] * res_w[oc * INCH + c];
    rp *= (1.f / (H * W));

    float4* p = reinterpret_cast<float4*>(out)
              + (size_t)bo * (OH * OW / 4) + (size_t)blockIdx.y * (OH * OW / 16);
    for (int i = threadIdx.x; i < OH * OW / 16; i += 256) {
        float4 v = p[i];
        v.x = fminf(fmaxf(fmaf(v.x, s, rp), -0.5f), 0.5f);
        v.y = fminf(fmaxf(fmaf(v.y, s, rp), -0.5f), 0.5f);
        v.z = fminf(fmaxf(fmaf(v.z, s, rp), -0.5f), 0.5f);
        v.w = fminf(fmaxf(fmaf(v.w, s, rp), -0.5f), 0.5f);
        p[i] = v;
    }
}

extern "C" void kernel_launch(void* const* d_in, const int* in_sizes, int n_in,
                              void* d_out, int out_size, void* d_ws, size_t ws_size,
                              hipStream_t stream) {
    const float* x      = (const float*)d_in[0];
    const float* weight = (const float*)d_in[1];
    const float* bias   = (const float*)d_in[2];
    const float* res_w  = (const float*)d_in[3];
    float* out = (float*)d_out;
    float* ws  = (float*)d_ws;

    init_ws<<<19, 256, 0, stream>>>(weight, ws);

    conv_act<<<dim3(36, 32), 256, 0, stream>>>(x, ws + WS_WT, bias,
                                               ws + WS_ACTSUM, ws + WS_POOLED, out);

    epilogue<<<dim3(512, 4), 256, 0, stream>>>(out, ws + WS_ACTSUM,
                                               ws + WS_POOLED, res_w);
}